// Round 12
// baseline (91.647 us; speedup 1.0000x reference)
//
#include <hip/hip_runtime.h>

#define Bn 32
#define Tn 16384
#define Ln 16
#define Sn 128
#define Hn 512
#define Cn 10
#define Kn 48
#define TOUT 16369
#define CH 1024
#define NCH 16

typedef short  s16x8  __attribute__((ext_vector_type(8)));
typedef float  f32x16 __attribute__((ext_vector_type(16)));

static __device__ __forceinline__ unsigned short f2bf(float f) {
    union { float f; unsigned int u; } v; v.f = f;
    unsigned int r = v.u + 0x7FFF + ((v.u >> 16) & 1);   // RNE
    return (unsigned short)(r >> 16);
}
static __device__ __forceinline__ float bf2f(unsigned short b) {
    union { unsigned int u; float f; } v; v.u = ((unsigned int)b) << 16;
    return v.f;
}
static __device__ __forceinline__ unsigned int pk(float a, float b) {
    return (unsigned int)f2bf(a) | ((unsigned int)f2bf(b) << 16);
}
static __device__ __forceinline__ unsigned int pk2(unsigned short a, unsigned short b) {
    return (unsigned int)a | ((unsigned int)b << 16);
}
static __device__ __forceinline__ s16x8 mk_a(unsigned int d0, unsigned int d1,
                                             unsigned int d2, unsigned int d3) {
    union { unsigned int u[4]; s16x8 v; } t;
    t.u[0] = d0; t.u[1] = d1; t.u[2] = d2; t.u[3] = d3;
    return t.v;
}

// ---------------------------------------------------------------- distance
// FULLY FUSED (no prep kernel): each lane loads its own 24-float x span,
// packs bf16 in-register, computes exact fp32 sliding winsq, folds
// winsq+shsq into the MFMA as a 4th K-channel (hi/lo bf16 split). B-frags
// convert from sh directly.
//
// LAUNCH BOUND IS LOAD-BEARING: (256,3) leaves only ~84 arch VGPRs (unified
// file) -> this exact kernel spilled 108 MB scratch and ran 64 us (R10).
// (256,2) budget ~168 fits the ~110-reg live set. DO NOT raise to 3.
__global__ __launch_bounds__(256, 2) void dist_kernel(const float* __restrict__ x,
                                                      const float* __restrict__ sh,
                                                      float* __restrict__ partial) {
    __shared__ float wavemin[4 * 64];

    const int tid   = threadIdx.x;
    const int b     = blockIdx.x >> 5;
    const int rem   = blockIdx.x & 31;
    const int chunk = rem >> 1;
    const int half  = rem & 1;                 // S-half: columns half*64 .. +63
    const int tb    = chunk * CH;
    const int lane  = tid & 63;
    const int w     = tid >> 6;
    const int n     = lane & 31;               // MFMA row (A) / col (B,C)
    const int h     = lane >> 5;               // k-half select

    // ---- 1) B-fragments (-2*sh, bf16) + shsq channel, from sh directly.
    s16x8 bfr[3][2], b4[2];
    #pragma unroll
    for (int st = 0; st < 2; ++st) {
        const int s = half * 64 + st * 32 + n;
        const float4* row4 = (const float4*)(sh + s * Kn);
        float q = 0.f;
        #pragma unroll
        for (int kk = 0; kk < 3; ++kk) {
            const float4 v0 = row4[kk * 4 + 0];
            const float4 v1 = row4[kk * 4 + 1];
            const float4 v2 = row4[kk * 4 + 2];
            const float4 v3 = row4[kk * 4 + 3];
            q = fmaf(v0.x, v0.x, q); q = fmaf(v0.y, v0.y, q);
            q = fmaf(v0.z, v0.z, q); q = fmaf(v0.w, v0.w, q);
            q = fmaf(v1.x, v1.x, q); q = fmaf(v1.y, v1.y, q);
            q = fmaf(v1.z, v1.z, q); q = fmaf(v1.w, v1.w, q);
            q = fmaf(v2.x, v2.x, q); q = fmaf(v2.y, v2.y, q);
            q = fmaf(v2.z, v2.z, q); q = fmaf(v2.w, v2.w, q);
            q = fmaf(v3.x, v3.x, q); q = fmaf(v3.y, v3.y, q);
            q = fmaf(v3.z, v3.z, q); q = fmaf(v3.w, v3.w, q);
            const float4 pa = h ? v2 : v0;
            const float4 pb = h ? v3 : v1;
            bfr[kk][st] = mk_a(pk(-2.f * pa.x, -2.f * pa.y),
                               pk(-2.f * pa.z, -2.f * pa.w),
                               pk(-2.f * pb.x, -2.f * pb.y),
                               pk(-2.f * pb.z, -2.f * pb.w));
        }
        const unsigned short qh = f2bf(q);
        const unsigned short ql = f2bf(q - bf2f(qh));
        b4[st] = h ? mk_a(0u, 0u, 0u, 0u)
                   : mk_a(0x3F803F80u, pk2(qh, ql), 0u, 0u);
    }

    // ---- 2) x span: 24 floats/lane/ch (aligned; guarded only in tail waves)
    //         -> bf16 window u[ch][8] + exact fp32 sliding winsq q8[8].
    const int t0 = tb + 8 * (w & 1) + ((w >> 1) << 9) + 16 * n + 8 * h;
    unsigned int u[3][8];
    float q8[8] = {0.f, 0.f, 0.f, 0.f, 0.f, 0.f, 0.f, 0.f};
    #pragma unroll
    for (int ch = 0; ch < 3; ++ch) {
        const float* xs = x + (b * 3 + ch) * Tn + t0;
        float wv[24];
        if (t0 + 24 <= Tn) {
            const float4* x4 = (const float4*)xs;
            #pragma unroll
            for (int c = 0; c < 6; ++c) {
                const float4 t = x4[c];
                wv[4*c] = t.x; wv[4*c+1] = t.y; wv[4*c+2] = t.z; wv[4*c+3] = t.w;
            }
        } else {
            #pragma unroll
            for (int k = 0; k < 24; ++k) wv[k] = (t0 + k < Tn) ? xs[k] : 0.f;
        }
        #pragma unroll
        for (int e = 0; e < 8; ++e) u[ch][e] = pk(wv[2*e], wv[2*e+1]);
        float s = 0.f;
        #pragma unroll
        for (int l = 0; l < 16; ++l) s = fmaf(wv[l], wv[l], s);
        q8[0] += s;
        #pragma unroll
        for (int j = 1; j < 8; ++j) {
            s = s - wv[j-1] * wv[j-1] + wv[j+15] * wv[j+15];
            q8[j] += s;
        }
    }
    // pack winsq hi/lo per rr (tail mask 1e30); only h==0 lanes' values used
    unsigned int wqp[8];
    #pragma unroll
    for (int rr = 0; rr < 8; ++rr) {
        const float qv = (t0 + rr >= TOUT) ? 1e30f : q8[rr];
        const unsigned short wh_ = f2bf(qv);
        const unsigned short wl_ = f2bf(qv - bf2f(wh_));
        wqp[rr] = pk2(wh_, wl_);
    }

    // ---- 3) main loop: 8 tiles, A-frags by static slice / v_alignbit
    float mcol[2] = {1e30f, 1e30f};
    const f32x16 zero16 = {0.f, 0.f, 0.f, 0.f, 0.f, 0.f, 0.f, 0.f,
                           0.f, 0.f, 0.f, 0.f, 0.f, 0.f, 0.f, 0.f};
    #pragma unroll
    for (int rr = 0; rr < 8; ++rr) {
        s16x8 a[3];
        #pragma unroll
        for (int ch = 0; ch < 3; ++ch) {
            if ((rr & 1) == 0) {
                a[ch] = mk_a(u[ch][rr/2], u[ch][rr/2+1], u[ch][rr/2+2], u[ch][rr/2+3]);
            } else {
                unsigned int d[4];
                #pragma unroll
                for (int k = 0; k < 4; ++k)
                    d[k] = (u[ch][rr/2 + k] >> 16) | (u[ch][rr/2 + k + 1] << 16);
                a[ch] = mk_a(d[0], d[1], d[2], d[3]);
            }
        }
        const s16x8 a4 = h ? mk_a(0u, 0u, 0u, 0u)
                           : mk_a(wqp[rr], 0x3F803F80u, 0u, 0u);

        #pragma unroll
        for (int st = 0; st < 2; ++st) {
            f32x16 acc;
            acc = __builtin_amdgcn_mfma_f32_32x32x16_bf16(a[0], bfr[0][st], zero16, 0, 0, 0);
            acc = __builtin_amdgcn_mfma_f32_32x32x16_bf16(a[1], bfr[1][st], acc, 0, 0, 0);
            acc = __builtin_amdgcn_mfma_f32_32x32x16_bf16(a[2], bfr[2][st], acc, 0, 0, 0);
            acc = __builtin_amdgcn_mfma_f32_32x32x16_bf16(a4,   b4[st],    acc, 0, 0, 0);
            #pragma unroll
            for (int reg = 0; reg < 16; reg += 2)
                mcol[st] = fminf(fminf(mcol[st], acc[reg]), acc[reg + 1]);   // v_min3
        }
    }

    // ---- 4) reduce: lanes n / n+32 share column
    #pragma unroll
    for (int st = 0; st < 2; ++st) {
        float mm = mcol[st];
        mm = fminf(mm, __shfl_xor(mm, 32, 64));
        if (h == 0) wavemin[w * 64 + st * 32 + n] = mm;
    }
    __syncthreads();
    if (tid < 64) {
        const float mm = fminf(fminf(wavemin[tid], wavemin[64 + tid]),
                               fminf(wavemin[128 + tid], wavemin[192 + tid]));
        partial[(b * NCH + chunk) * Sn + half * 64 + tid] = mm;
    }
}

// ------------------------------------------- final min over chunks + MLP head
__global__ __launch_bounds__(512) void mlp_kernel(const float* __restrict__ partial,
                                                  const float* __restrict__ W1,
                                                  const float* __restrict__ b1,
                                                  const float* __restrict__ W2,
                                                  const float* __restrict__ b2,
                                                  float* __restrict__ out) {
    __shared__ float pmin[4][Sn];
    __shared__ float db[Sn];
    __shared__ float hb[Hn];
    __shared__ float part[Cn][32];
    const int b = blockIdx.x, tid = threadIdx.x;

    {
        const int s = tid & 127, g = tid >> 7;
        const float* pp = partial + (b * NCH + g * 4) * Sn + s;
        float m = pp[0];
        #pragma unroll
        for (int c = 1; c < 4; ++c) m = fminf(m, pp[c * Sn]);
        pmin[g][s] = m;
    }
    __syncthreads();
    if (tid < Sn) {
        const float m = fminf(fminf(pmin[0][tid], pmin[1][tid]),
                              fminf(pmin[2][tid], pmin[3][tid]));
        db[tid] = m;
        out[b * Sn + tid] = m;             // distance output
    }
    __syncthreads();

    float a = b1[tid];
    const float4* w1r = (const float4*)(W1 + tid * Sn);
    const float4* dbv = (const float4*)db;
    #pragma unroll
    for (int i = 0; i < Sn / 4; ++i) {
        const float4 wv = w1r[i];
        const float4 dv = dbv[i];
        a = fmaf(dv.x, wv.x, a); a = fmaf(dv.y, wv.y, a);
        a = fmaf(dv.z, wv.z, a); a = fmaf(dv.w, wv.w, a);
    }
    hb[tid] = fmaxf(a, 0.0f);
    __syncthreads();

    if (tid < Cn * 32) {
        const int c = tid >> 5, p = tid & 31;
        float acc = 0.f;
        #pragma unroll
        for (int i = 0; i < Hn / 32; ++i)
            acc = fmaf(hb[p + 32 * i], W2[c * Hn + p + 32 * i], acc);
        part[c][p] = acc;
    }
    __syncthreads();
    if (tid < Cn) {
        float acc = b2[tid];
        #pragma unroll
        for (int p = 0; p < 32; ++p) acc += part[tid][p];
        out[Bn * Sn + b * Cn + tid] = acc; // classification output
    }
}

// ----------------------------------------------------------------- launcher
extern "C" void kernel_launch(void* const* d_in, const int* in_sizes, int n_in,
                              void* d_out, int out_size, void* d_ws, size_t ws_size,
                              hipStream_t stream) {
    const float* x  = (const float*)d_in[0];
    const float* sh = (const float*)d_in[1];
    const float* W1 = (const float*)d_in[2];
    const float* b1 = (const float*)d_in[3];
    const float* W2 = (const float*)d_in[4];
    const float* b2 = (const float*)d_in[5];
    float* out = (float*)d_out;
    float* partial = (float*)d_ws;   // 32*16*128 floats = 256 KB

    dist_kernel<<<Bn * NCH * 2, 256, 0, stream>>>(x, sh, partial);
    mlp_kernel<<<Bn, 512, 0, stream>>>(partial, W1, b1, W2, b2, out);
}

// Round 13
// 85.505 us; speedup vs baseline: 1.0718x; 1.0718x over previous
//
#include <hip/hip_runtime.h>

#define Bn 32
#define Tn 16384
#define Ln 16
#define Sn 128
#define Hn 512
#define Cn 10
#define Kn 48
#define TOUT 16369
#define CH 1024
#define NCH 16
#define XBP 8224   // dwords per (b,ch) row of xbf (8192 + 32 zero pad)

typedef short  s16x8  __attribute__((ext_vector_type(8)));
typedef float  f32x16 __attribute__((ext_vector_type(16)));

static __device__ __forceinline__ unsigned short f2bf(float f) {
    union { float f; unsigned int u; } v; v.f = f;
    unsigned int r = v.u + 0x7FFF + ((v.u >> 16) & 1);   // RNE
    return (unsigned short)(r >> 16);
}
static __device__ __forceinline__ float bf2f(unsigned short b) {
    union { unsigned int u; float f; } v; v.u = ((unsigned int)b) << 16;
    return v.f;
}
static __device__ __forceinline__ unsigned int pk(float a, float b) {
    return (unsigned int)f2bf(a) | ((unsigned int)f2bf(b) << 16);
}
static __device__ __forceinline__ unsigned int pk2(unsigned short a, unsigned short b) {
    return (unsigned int)a | ((unsigned int)b << 16);
}
static __device__ __forceinline__ s16x8 mk_a(unsigned int d0, unsigned int d1,
                                             unsigned int d2, unsigned int d3) {
    union { unsigned int u[4]; s16x8 v; } t;
    t.u[0] = d0; t.u[1] = d1; t.u[2] = d2; t.u[3] = d3;
    return t.v;
}

// ------------------------------------------------------------------ prologue
// Cheap memory-bound precompute at full occupancy. R12 proved fusing this
// into dist costs ~+8us (conversion VALU at 8 waves/CU) vs ~-2.5us saved.
__global__ __launch_bounds__(256) void prep_kernel(const float* __restrict__ x,
                                                   const float* __restrict__ sh,
                                                   const float* __restrict__ b2,
                                                   unsigned int* __restrict__ shb,
                                                   float* __restrict__ shsq_g,
                                                   float* __restrict__ wsqT,
                                                   unsigned int* __restrict__ xbf,
                                                   float* __restrict__ out) {
    const int tid = threadIdx.x;
    if (blockIdx.x == 0) {
        if (tid < 128) {
            const float4* r4 = (const float4*)(sh + tid * Kn);
            float v[48]; float q = 0.f;
            #pragma unroll
            for (int c = 0; c < 12; ++c) {
                const float4 t = r4[c];
                v[4*c] = t.x; v[4*c+1] = t.y; v[4*c+2] = t.z; v[4*c+3] = t.w;
                q = fmaf(t.x, t.x, q); q = fmaf(t.y, t.y, q);
                q = fmaf(t.z, t.z, q); q = fmaf(t.w, t.w, q);
            }
            shsq_g[tid] = q;
            uint4* dst = (uint4*)(shb + tid * 24);
            #pragma unroll
            for (int c = 0; c < 6; ++c) {
                uint4 o;
                o.x = pk(-2.f*v[8*c  ], -2.f*v[8*c+1]);
                o.y = pk(-2.f*v[8*c+2], -2.f*v[8*c+3]);
                o.z = pk(-2.f*v[8*c+4], -2.f*v[8*c+5]);
                o.w = pk(-2.f*v[8*c+6], -2.f*v[8*c+7]);
                dst[c] = o;
            }
        } else if (tid < 224) {
            const int r = tid - 128;             // 96 rows: zero 32-dword pads
            uint4* d = (uint4*)(xbf + r * XBP + 8192);
            const uint4 z = {0u, 0u, 0u, 0u};
            #pragma unroll
            for (int q = 0; q < 8; ++q) d[q] = z;
        } else {
            const int k0 = (tid - 224) * 10;     // init out[cls] = b2 (mlp atomicAdds)
            #pragma unroll
            for (int c = 0; c < Cn; ++c) out[Bn * Sn + k0 + c] = b2[c];
        }
        return;
    }
    // blocks 1..512: (b, 1024-t slab); thread owns 4 t
    const int bid = blockIdx.x - 1;
    const int b   = bid >> 4;
    const int t0  = ((bid & 15) << 10) + 4 * tid;
    float q[4] = {0.f, 0.f, 0.f, 0.f};
    #pragma unroll
    for (int ch = 0; ch < 3; ++ch) {
        const float* xs = x + (b * 3 + ch) * Tn + t0;
        float wv[20];
        if (t0 + 20 <= Tn) {
            const float4* x4 = (const float4*)xs;
            #pragma unroll
            for (int c = 0; c < 5; ++c) {
                const float4 t = x4[c];
                wv[4*c] = t.x; wv[4*c+1] = t.y; wv[4*c+2] = t.z; wv[4*c+3] = t.w;
            }
        } else {
            #pragma unroll
            for (int k = 0; k < 20; ++k) wv[k] = (t0 + k < Tn) ? xs[k] : 0.f;
        }
        float s = 0.f;
        #pragma unroll
        for (int l = 0; l < 16; ++l) s = fmaf(wv[l], wv[l], s);
        q[0] += s;
        #pragma unroll
        for (int j = 1; j < 4; ++j) {
            s = s - wv[j-1]*wv[j-1] + wv[j+15]*wv[j+15];
            q[j] += s;
        }
        uint2 o = { pk(wv[0], wv[1]), pk(wv[2], wv[3]) };
        *(uint2*)(xbf + (b * 3 + ch) * XBP + (t0 >> 1)) = o;
    }
    const int r0 = t0 & 15, col = t0 >> 4;
    float* wrow = wsqT + b * 16384 + col;
    #pragma unroll
    for (int c = 0; c < 4; ++c)
        wrow[(r0 + c) * 1024] = (t0 + c >= TOUT) ? 1e30f : q[c];
}

// ---------------------------------------------------------------- distance
// (256,2): R10/R12 proved the (256,3) arch-VGPR budget is only ~84 (unified
// file reserves the rest for accum) — this kernel's ~110-reg live set spills
// ~100MB scratch there (R10: 64us). (256,2) budget ~168 fits. DO NOT raise.
__global__ __launch_bounds__(256, 2) void dist_kernel(const unsigned int* __restrict__ shb,
                                                      const float* __restrict__ shsq_g,
                                                      const float* __restrict__ wsqT,
                                                      const unsigned int* __restrict__ xbf,
                                                      float* __restrict__ partial) {
    __shared__ float wavemin[4 * 64];

    const int tid   = threadIdx.x;
    const int b     = blockIdx.x >> 5;
    const int rem   = blockIdx.x & 31;
    const int chunk = rem >> 1;
    const int half  = rem & 1;                   // S-half: columns half*64 .. +63
    const int tb    = chunk * CH;
    const int lane  = tid & 63;
    const int w     = tid >> 6;
    const int n     = lane & 31;
    const int h     = lane >> 5;

    // ---- B-fragments: 3 data channels + winsq/shsq channel b4
    s16x8 bfr[3][2], b4[2];
    #pragma unroll
    for (int st = 0; st < 2; ++st) {
        const int s = half * 64 + st * 32 + n;
        const uint4* base = (const uint4*)(shb + s * 24);
        #pragma unroll
        for (int kk = 0; kk < 3; ++kk) {
            const uint4 t = base[kk * 2 + h];
            bfr[kk][st] = mk_a(t.x, t.y, t.z, t.w);
        }
        const float q = shsq_g[s];
        const unsigned short qh = f2bf(q);
        const unsigned short ql = f2bf(q - bf2f(qh));
        b4[st] = h ? mk_a(0u, 0u, 0u, 0u)
                   : mk_a(0x3F803F80u, pk2(qh, ql), 0u, 0u);
    }

    // ---- rr-invariant 16-elem bf16 window per channel (16-B aligned loads)
    unsigned int u[3][8];
    {
        const int D0 = (tb >> 1) + 4 * (w & 1) + ((w >> 1) << 8) + 8 * n + 4 * h;
        #pragma unroll
        for (int ch = 0; ch < 3; ++ch) {
            const unsigned int* xr = xbf + (b * 3 + ch) * XBP + D0;
            const uint4 lo = *(const uint4*)(xr);
            const uint4 hi = *(const uint4*)(xr + 4);
            u[ch][0] = lo.x; u[ch][1] = lo.y; u[ch][2] = lo.z; u[ch][3] = lo.w;
            u[ch][4] = hi.x; u[ch][5] = hi.y; u[ch][6] = hi.z; u[ch][7] = hi.w;
        }
    }

    // ---- main loop: 8 tiles, 8 MFMA each (4 per st incl. the w/shsq channel)
    float mcol[2] = {1e30f, 1e30f};
    const f32x16 zero16 = {0.f, 0.f, 0.f, 0.f, 0.f, 0.f, 0.f, 0.f,
                           0.f, 0.f, 0.f, 0.f, 0.f, 0.f, 0.f, 0.f};
    const int   base_t = 8 * (w & 1) + ((w >> 1) << 9);
    const float* wbase = wsqT + b * 16384 + (tb >> 4) + n;

    #pragma unroll
    for (int rr = 0; rr < 8; ++rr) {
        const int i = base_t + rr;
        s16x8 a[3];
        #pragma unroll
        for (int ch = 0; ch < 3; ++ch) {
            if ((rr & 1) == 0) {
                a[ch] = mk_a(u[ch][rr/2], u[ch][rr/2+1], u[ch][rr/2+2], u[ch][rr/2+3]);
            } else {
                unsigned int d[4];
                #pragma unroll
                for (int k = 0; k < 4; ++k)
                    d[k] = (u[ch][rr/2 + k] >> 16) | (u[ch][rr/2 + k + 1] << 16);
                a[ch] = mk_a(d[0], d[1], d[2], d[3]);
            }
        }
        // winsq channel: coalesced per-lane load + hi/lo bf16 split
        const float wv = wbase[(i & 15) * 1024 + ((i >> 9) << 5)];
        const unsigned short wh = f2bf(wv);
        const unsigned short wl = f2bf(wv - bf2f(wh));
        const s16x8 a4 = h ? mk_a(0u, 0u, 0u, 0u)
                           : mk_a(pk2(wh, wl), 0x3F803F80u, 0u, 0u);

        #pragma unroll
        for (int st = 0; st < 2; ++st) {
            f32x16 acc;
            acc = __builtin_amdgcn_mfma_f32_32x32x16_bf16(a[0], bfr[0][st], zero16, 0, 0, 0);
            acc = __builtin_amdgcn_mfma_f32_32x32x16_bf16(a[1], bfr[1][st], acc, 0, 0, 0);
            acc = __builtin_amdgcn_mfma_f32_32x32x16_bf16(a[2], bfr[2][st], acc, 0, 0, 0);
            acc = __builtin_amdgcn_mfma_f32_32x32x16_bf16(a4,   b4[st],    acc, 0, 0, 0);
            #pragma unroll
            for (int reg = 0; reg < 16; reg += 2)
                mcol[st] = fminf(fminf(mcol[st], acc[reg]), acc[reg + 1]);   // v_min3
        }
    }

    // ---- reduce: lanes n / n+32 share column
    #pragma unroll
    for (int st = 0; st < 2; ++st) {
        float mm = mcol[st];
        mm = fminf(mm, __shfl_xor(mm, 32, 64));
        if (h == 0) wavemin[w * 64 + st * 32 + n] = mm;
    }
    __syncthreads();
    if (tid < 64) {
        const float mm = fminf(fminf(wavemin[tid], wavemin[64 + tid]),
                               fminf(wavemin[128 + tid], wavemin[192 + tid]));
        partial[(b * NCH + chunk) * Sn + half * 64 + tid] = mm;
    }
}

// ------------------------- final min + MLP, H split over 4 blocks per batch
__global__ __launch_bounds__(512) void mlp_kernel(const float* __restrict__ partial,
                                                  const float* __restrict__ W1,
                                                  const float* __restrict__ b1,
                                                  const float* __restrict__ W2,
                                                  float* __restrict__ out) {
    __shared__ float pmin[4][Sn];
    __shared__ float db[Sn];
    __shared__ float hb[128];
    __shared__ float part[Cn][32];
    const int b = blockIdx.x >> 2, g = blockIdx.x & 3, tid = threadIdx.x;

    {
        const int s = tid & 127, cg = tid >> 7;
        const float* pp = partial + (b * NCH + cg * 4) * Sn + s;
        float m = pp[0];
        #pragma unroll
        for (int c = 1; c < 4; ++c) m = fminf(m, pp[c * Sn]);
        pmin[cg][s] = m;
    }
    __syncthreads();
    if (tid < Sn) {
        const float m = fminf(fminf(pmin[0][tid], pmin[1][tid]),
                              fminf(pmin[2][tid], pmin[3][tid]));
        db[tid] = m;
        if (g == 0) out[b * Sn + tid] = m;     // distance output
    }
    __syncthreads();

    if (tid < 128) {                            // h rows g*128 .. +127
        const int hrow = g * 128 + tid;
        float a = b1[hrow];
        const float4* w1r = (const float4*)(W1 + hrow * Sn);
        const float4* dbv = (const float4*)db;
        #pragma unroll
        for (int i = 0; i < Sn / 4; ++i) {
            const float4 wv = w1r[i];
            const float4 dv = dbv[i];
            a = fmaf(dv.x, wv.x, a); a = fmaf(dv.y, wv.y, a);
            a = fmaf(dv.z, wv.z, a); a = fmaf(dv.w, wv.w, a);
        }
        hb[tid] = fmaxf(a, 0.0f);
    }
    __syncthreads();

    if (tid < Cn * 32) {
        const int c = tid >> 5, p = tid & 31;
        float acc = 0.f;
        #pragma unroll
        for (int k = 0; k < 4; ++k)
            acc = fmaf(hb[p + 32 * k], W2[c * Hn + g * 128 + p + 32 * k], acc);
        part[c][p] = acc;
    }
    __syncthreads();
    if (tid < Cn) {
        float acc = 0.f;
        #pragma unroll
        for (int p = 0; p < 32; ++p) acc += part[tid][p];
        atomicAdd(&out[Bn * Sn + b * Cn + tid], acc);   // b2 pre-added by prep
    }
}

// ----------------------------------------------------------------- launcher
extern "C" void kernel_launch(void* const* d_in, const int* in_sizes, int n_in,
                              void* d_out, int out_size, void* d_ws, size_t ws_size,
                              hipStream_t stream) {
    const float* x  = (const float*)d_in[0];
    const float* sh = (const float*)d_in[1];
    const float* W1 = (const float*)d_in[2];
    const float* b1 = (const float*)d_in[3];
    const float* W2 = (const float*)d_in[4];
    const float* b2 = (const float*)d_in[5];
    float* out = (float*)d_out;

    char* wsb = (char*)d_ws;
    float*        partial = (float*)wsb;                    // 262144 B
    unsigned int* shb     = (unsigned int*)(wsb + 262144);  //  12288 B
    float*        shsq_g  = (float*)(wsb + 274432);         //    512 B
    float*        wsqT    = (float*)(wsb + 278528);         //   2 MiB
    unsigned int* xbf     = (unsigned int*)(wsb + 2375680); //   3.2 MiB

    prep_kernel<<<513, 256, 0, stream>>>(x, sh, b2, shb, shsq_g, wsqT, xbf, out);
    dist_kernel<<<Bn * NCH * 2, 256, 0, stream>>>(shb, shsq_g, wsqT, xbf, partial);
    mlp_kernel<<<Bn * 4, 512, 0, stream>>>(partial, W1, b1, W2, out);
}